// Round 1
// baseline (31.027 us; speedup 1.0000x reference)
//
#include <hip/hip_runtime.h>
#include <stdint.h>

#define BATCH 128
#define NELEM 33600
#define NCH 6
#define TOPK 300
#define NTHREADS 1024
#define PER_THREAD 33   // ceil(33600/1024)
#define CAP 768

__device__ __forceinline__ uint32_t fkey(float f) {
    uint32_t u = __float_as_uint(f);
    // order-preserving map: descending float == descending unsigned key
    return (u & 0x80000000u) ? ~u : (u | 0x80000000u);
}

__global__ __launch_bounds__(NTHREADS) void yolo_post_topk(
    const float* __restrict__ preds, float* __restrict__ out)
{
    const int b   = blockIdx.x;
    const int tid = threadIdx.x;
    const int wave = tid >> 6;
    const float* row = preds + (size_t)b * (NELEM * NCH);

    __shared__ uint32_t hist[256][16];   // per-wave privatized MSB histogram
    __shared__ uint32_t suf[257];
    __shared__ uint32_t h2[257];
    __shared__ uint64_t cand[CAP];
    __shared__ uint32_t ccount;
    __shared__ uint32_t sh_b1, sh_S1, sh_thr;

    // ---- zero LDS ----
    for (int i = tid; i < 256 * 16; i += NTHREADS) ((uint32_t*)hist)[i] = 0;
    if (tid == 0) ccount = 0;
    __syncthreads();

    // ---- phase 1: load scores -> keys in registers + 8-bit histogram ----
    uint32_t key[PER_THREAD];
    #pragma unroll
    for (int j = 0; j < PER_THREAD; ++j) {
        int i = tid + j * NTHREADS;
        if (i < NELEM) {
            float s = row[(size_t)i * NCH + 4];
            uint32_t k = fkey(s);
            key[j] = k;
            atomicAdd(&hist[k >> 24][wave], 1u);
        } else {
            key[j] = 0u;
        }
    }
    __syncthreads();

    // ---- merge per-wave histograms ----
    if (tid < 256) {
        uint32_t s = 0;
        #pragma unroll
        for (int w = 0; w < 16; ++w) s += hist[tid][w];
        suf[tid] = s;
        if (tid == 0) suf[256] = 0;
    }
    __syncthreads();

    // ---- suffix scan (Hillis-Steele, 8 steps): suf[b] = count(bin >= b) ----
    for (int d = 1; d < 256; d <<= 1) {
        uint32_t t = 0;
        if (tid < 256 && tid + d < 256) t = suf[tid + d];
        __syncthreads();
        if (tid < 256) suf[tid] += t;
        __syncthreads();
    }
    if (tid < 256) {
        uint32_t hi = (tid == 255) ? 0u : suf[tid + 1];
        if (suf[tid] >= TOPK && hi < TOPK) { sh_b1 = (uint32_t)tid; sh_S1 = hi; }
    }
    if (tid < 257) h2[tid] = 0;
    __syncthreads();
    const uint32_t b1 = sh_b1, S1 = sh_S1;

    // ---- phase 2: refine within bin b1 over key bits [23:16] ----
    #pragma unroll
    for (int j = 0; j < PER_THREAD; ++j) {
        int i = tid + j * NTHREADS;
        if (i < NELEM && (key[j] >> 24) == b1)
            atomicAdd(&h2[(key[j] >> 16) & 0xFFu], 1u);
    }
    __syncthreads();
    for (int d = 1; d < 256; d <<= 1) {
        uint32_t t = 0;
        if (tid < 256 && tid + d < 256) t = h2[tid + d];
        __syncthreads();
        if (tid < 256) h2[tid] += t;
        __syncthreads();
    }
    if (tid < 256) {
        uint32_t hi = (tid == 255) ? 0u : h2[tid + 1];
        if (S1 + h2[tid] >= TOPK && S1 + hi < TOPK)
            sh_thr = (b1 << 8) | (uint32_t)tid;
    }
    __syncthreads();
    const uint32_t thr = sh_thr;

    // ---- collect candidates: all keys with (key>>16) >= thr  (~315) ----
    #pragma unroll
    for (int j = 0; j < PER_THREAD; ++j) {
        int i = tid + j * NTHREADS;
        if (i < NELEM && (key[j] >> 16) >= thr) {
            uint32_t pos = atomicAdd(&ccount, 1u);
            if (pos < CAP)
                cand[pos] = ((uint64_t)key[j] << 32) | (uint32_t)(~(uint32_t)i);
        }
    }
    __syncthreads();
    const int Cn = (int)min(ccount, (uint32_t)CAP);

    // ---- rank by counting (desc key, asc index on ties), then emit ----
    if (tid < Cn) {
        const uint64_t mine = cand[tid];
        int rank = 0;
        for (int j = 0; j < Cn; ++j) rank += (cand[j] > mine) ? 1 : 0;
        if (rank < TOPK) {
            uint32_t idx = ~(uint32_t)(mine & 0xFFFFFFFFu);
            const float* e = row + (size_t)idx * NCH;
            float p0 = e[0], p1 = e[1], p2 = e[2], p3 = e[3], p4 = e[4], p5 = e[5];
            const float inv = 1.0f / 1280.0f;
            float x1 = p0 * inv, y1 = p1 * inv, x2 = p2 * inv, y2 = p3 * inv;
            float* o = out + (size_t)b * (TOPK * NCH) + (size_t)rank * NCH;
            o[0] = (x1 + x2) * 0.5f;
            o[1] = (y1 + y2) * 0.5f;
            o[2] = x2 - x1;
            o[3] = y2 - y1;
            o[4] = p4;
            o[5] = p5;
        }
    }
}

extern "C" void kernel_launch(void* const* d_in, const int* in_sizes, int n_in,
                              void* d_out, int out_size, void* d_ws, size_t ws_size,
                              hipStream_t stream) {
    const float* preds = (const float*)d_in[0];
    float* out = (float*)d_out;
    hipLaunchKernelGGL(yolo_post_topk, dim3(BATCH), dim3(NTHREADS), 0, stream,
                       preds, out);
}